// Round 9
// baseline (2319.582 us; speedup 1.0000x reference)
//
#include <hip/hip_runtime.h>
#include <stdint.h>

#define NSN 20
#define NPN 8
#define NB 128
#define TT 24
#define NN 28
#define ES 100
#define EP 32
#define KHS 1280
#define KHP 768
#define NPRE 768
#define TCH 4

typedef _Float16 half_t;
typedef __attribute__((ext_vector_type(8))) _Float16 f16x8;
typedef __attribute__((ext_vector_type(4))) float f32x4;

__device__ __forceinline__ void gl16(const half_t* g, half_t* l) {
  __builtin_amdgcn_global_load_lds((const __attribute__((address_space(1))) void*)g,
                                   (__attribute__((address_space(3))) void*)l, 16, 0, 0);
}

// ---------------- graph build (edges staged in LDS) ----------------
__global__ void graph_build(const int* __restrict__ ei_s, const float* __restrict__ ew_s,
                            const int* __restrict__ ei_p, const float* __restrict__ ew_p,
                            float* __restrict__ Ms_s, float* __restrict__ Ms_p,
                            float* __restrict__ Mbig_s, float* __restrict__ Mbig_p) {
  __shared__ float Ao[NSN*NSN], Aiw[NSN*NSN], dgo[NSN], dgi[NSN];
  __shared__ float T2o[NSN*NSN], T2i[NSN*NSN];
  __shared__ float Aop[NPN*NPN], Aip[NPN*NPN], dgop[NPN], dgip[NPN];
  __shared__ int eis[2*ES]; __shared__ float ews[ES];
  __shared__ int eip[2*EP]; __shared__ float ewp[EP];
  int tid = threadIdx.x;
  for (int i = tid; i < 2*ES; i += blockDim.x) eis[i] = ei_s[i];
  for (int i = tid; i < ES; i += blockDim.x) ews[i] = ew_s[i];
  for (int i = tid; i < 2*EP; i += blockDim.x) eip[i] = ei_p[i];
  for (int i = tid; i < EP; i += blockDim.x) ewp[i] = ew_p[i];
  for (int i = tid; i < NSN*NSN; i += blockDim.x) { Ao[i] = 0.f; Aiw[i] = 0.f; }
  for (int i = tid; i < NPN*NPN; i += blockDim.x) { Aop[i] = 0.f; Aip[i] = 0.f; }
  if (tid < NSN) { dgo[tid] = 0.f; dgi[tid] = 0.f; }
  if (tid < NPN) { dgop[tid] = 0.f; dgip[tid] = 0.f; }
  __syncthreads();
  if (tid == 0) {
    for (int e = 0; e < ES; ++e) { int r = eis[e], c = eis[ES+e]; float w = ews[e]; dgo[r] += w; dgi[c] += w; }
    for (int e = 0; e < ES; ++e) { int r = eis[e], c = eis[ES+e]; Ao[c*NSN+r] += 1.f/dgo[r]; Aiw[c*NSN+r] += 1.f/dgi[r]; }
  }
  if (tid == 1) {
    for (int e = 0; e < EP; ++e) { int r = eip[e], c = eip[EP+e]; float w = ewp[e]; dgop[r] += w; dgip[c] += w; }
    for (int e = 0; e < EP; ++e) { int r = eip[e], c = eip[EP+e]; Aop[c*NPN+r] += 1.f/dgop[r]; Aip[c*NPN+r] += 1.f/dgip[r]; }
  }
  __syncthreads();
  for (int i = tid; i < NSN*NSN; i += blockDim.x) {
    int r = i / NSN, c = i % NSN;
    float so = 0.f, si = 0.f;
    for (int k = 0; k < NSN; ++k) { so += Ao[r*NSN+k]*Ao[k*NSN+c]; si += Aiw[r*NSN+k]*Aiw[k*NSN+c]; }
    float t2o = 2.f*so - (r==c ? 1.f : 0.f);
    float t2i = 2.f*si - (r==c ? 1.f : 0.f);
    T2o[i] = t2o; T2i[i] = t2i;
    Ms_s[0*NSN*NSN + i] = Ao[i];
    Ms_s[1*NSN*NSN + i] = Aiw[i];
    Ms_s[2*NSN*NSN + i] = t2o;
    Ms_s[3*NSN*NSN + i] = t2i;
  }
  for (int i = tid; i < NPN*NPN; i += blockDim.x) {
    Ms_p[0*NPN*NPN + i] = Aop[i];
    Ms_p[1*NPN*NPN + i] = Aip[i];
  }
  __syncthreads();
  for (int i = tid; i < NSN*NSN*5; i += blockDim.x) {
    int n = i / 100, s = i % 100, r = s / 5, tau = s % 5;
    float v;
    if (tau == 0) v = (n == r) ? 1.f : 0.f;
    else if (tau == 1) v = Ao[n*NSN + r];
    else if (tau == 2) v = Aiw[n*NSN + r];
    else if (tau == 3) v = T2o[n*NSN + r];
    else               v = T2i[n*NSN + r];
    Mbig_s[i] = v;
  }
  for (int i = tid; i < NPN*NPN*3; i += blockDim.x) {
    int n = i / 24, s = i % 24, r = s / 3, tau = s % 3;
    float v;
    if (tau == 0) v = (n == r) ? 1.f : 0.f;
    else if (tau == 1) v = Aop[n*NPN + r];
    else               v = Aip[n*NPN + r];
    Mbig_p[i] = v;
  }
}

// ---------------- weight prep (fp16) ----------------
__device__ __forceinline__ float wsrc(const float* W, int Kdim, int tau, int i, int jj) {
  if (tau == 0) return W[(size_t)(0*Kdim+0)*512*256 + (size_t)i*256 + jj]
                     + W[(size_t)(1*Kdim+0)*512*256 + (size_t)i*256 + jj];
  int dir = (tau - 1) & 1;
  int k = (tau + 1) >> 1;
  return W[(size_t)(dir*Kdim + k)*512*256 + (size_t)i*256 + jj];
}

__global__ void prep_w(const float* __restrict__ Wz_s, const float* __restrict__ Wr_s, const float* __restrict__ Wh_s,
                       const float* __restrict__ Wz_p, const float* __restrict__ Wr_p, const float* __restrict__ Wh_p,
                       half_t* __restrict__ WX_s, half_t* __restrict__ WX_p,
                       half_t* __restrict__ WHzr_s, half_t* __restrict__ WHh_s,
                       half_t* __restrict__ WHzr_p, half_t* __restrict__ WHh_p) {
  const long c0 = (long)768*KHS;
  const long c1 = c0 + (long)768*KHP;
  const long c2 = c1 + (long)2560*256;
  const long c3 = c2 + (long)1280*256;
  const long c4 = c3 + (long)1536*256;
  const long c5 = c4 + (long)768*256;
  for (long idx = (long)blockIdx.x*256 + threadIdx.x; idx < c5; idx += (long)gridDim.x*256) {
    if (idx < c0) {
      long x = idx; int j = (int)(x / KHS), c = (int)(x % KHS); int tau = c >> 8;
      const float* W = (j < 256) ? Wz_s : (j < 512) ? Wr_s : Wh_s;
      WX_s[x] = (half_t)wsrc(W, 3, tau, c & 255, j & 255);
    } else if (idx < c1) {
      long x = idx - c0; int j = (int)(x / KHP), c = (int)(x % KHP); int tau = c >> 8;
      const float* W = (j < 256) ? Wz_p : (j < 512) ? Wr_p : Wh_p;
      WX_p[x] = (half_t)wsrc(W, 2, tau, c & 255, j & 255);
    } else if (idx < c2) {
      long x = idx - c1; int cc = (int)(x >> 8), f = (int)(x & 255);
      int tau = cc / 512, j = cc % 512;
      const float* W = (j < 256) ? Wz_s : Wr_s;
      WHzr_s[(size_t)cc*256 + f] = (half_t)wsrc(W, 3, tau, 256 + f, j & 255);
    } else if (idx < c3) {
      long x = idx - c2; int cc = (int)(x >> 8), f = (int)(x & 255);
      int tau = cc >> 8, j = cc & 255;
      WHh_s[(size_t)cc*256 + f] = (half_t)wsrc(Wh_s, 3, tau, 256 + f, j);
    } else if (idx < c4) {
      long x = idx - c3; int cc = (int)(x >> 8), f = (int)(x & 255);
      int tau = cc / 512, j = cc % 512;
      const float* W = (j < 256) ? Wz_p : Wr_p;
      WHzr_p[(size_t)cc*256 + f] = (half_t)wsrc(W, 2, tau, 256 + f, j & 255);
    } else {
      long x = idx - c4; int cc = (int)(x >> 8), f = (int)(x & 255);
      int tau = cc >> 8, j = cc & 255;
      WHh_p[(size_t)cc*256 + f] = (half_t)wsrc(Wh_p, 2, tau, 256 + f, j);
    }
  }
}

__global__ void zero_f(float* p, long n) {
  long i = (long)blockIdx.x*256 + threadIdx.x;
  if (i < n) p[i] = 0.f;
}

// ---------------- cheb expansion of X (precompute A), fp16 ----------------
__global__ __launch_bounds__(256) void chebx(const float* __restrict__ xdis, const float* __restrict__ xpre,
                                             const float* __restrict__ Ms_s, const float* __restrict__ Ms_p,
                                             half_t* __restrict__ XTs, half_t* __restrict__ XTp, int t0) {
  __shared__ float Xc[NSN*256];
  __shared__ float Ml[4*NSN*NSN];
  int bb = blockIdx.x, tid = threadIdx.x;
  bool isP = bb >= NB*TCH;
  int q = isP ? bb - NB*TCH : bb;
  int b = q % NB, tp = q / NB;
  int N = isP ? NPN : NSN, nt = isP ? 3 : 5, KX = nt << 8;
  const float* X = isP ? (xpre + (size_t)(b*TT + t0 + tp)*NPN*256)
                       : (xdis + (size_t)(b*TT + t0 + tp)*NSN*256);
  for (int i = tid; i < N*64; i += 256) ((float4*)Xc)[i] = ((const float4*)X)[i];
  int nm = (nt-1)*N*N;
  const float* Msrc = isP ? Ms_p : Ms_s;
  for (int i = tid; i < nm; i += 256) Ml[i] = Msrc[i];
  __syncthreads();
  half_t* XT = isP ? XTp : XTs;
  size_t rowbase = (size_t)(tp*NB + b)*N;
  int kc8 = KX >> 3, nch = N * kc8;
  for (int i = tid; i < nch; i += 256) {
    int n = i / kc8, c8 = i - n*kc8;
    int tau = c8 >> 5, f0 = (c8 & 31) << 3;
    float v[8];
    if (tau == 0) {
      const float* xr0 = Xc + n*256 + f0;
#pragma unroll
      for (int j = 0; j < 8; ++j) v[j] = xr0[j];
    } else {
      const float* M = Ml + (tau-1)*N*N + n*N;
#pragma unroll
      for (int j = 0; j < 8; ++j) v[j] = 0.f;
      for (int r = 0; r < N; ++r) {
        float m = M[r];
        const float* xr = Xc + r*256 + f0;
#pragma unroll
        for (int j = 0; j < 8; ++j) v[j] += m*xr[j];
      }
    }
    union { uint4 q; half_t u[8]; } hv;
#pragma unroll
    for (int j = 0; j < 8; ++j) hv.u[j] = (half_t)v[j];
    *(uint4*)(XT + (rowbase + n)*(size_t)KX + ((size_t)c8 << 3)) = hv.q;
  }
}

// ---------------- precompute GEMM (unchanged from R8) ----------------
__global__ __launch_bounds__(512) void gemm_pre(
    const half_t* __restrict__ A0, const half_t* __restrict__ B0, int K0,
    int rbS, int cbTot,
    const half_t* __restrict__ A1, const half_t* __restrict__ B1, int K1,
    half_t* __restrict__ Px0, half_t* __restrict__ Px1,
    const float* __restrict__ bz0, const float* __restrict__ br0, const float* __restrict__ bh0,
    const float* __restrict__ bz1, const float* __restrict__ br1, const float* __restrict__ bh1) {
  __shared__ __align__(16) half_t sbuf[3][12288];
  int id = blockIdx.x;
  int xx = id & 7, kq = id >> 3;
  int rbTot8 = (gridDim.x / cbTot) >> 3;
  int rb = xx*rbTot8 + kq / cbTot;
  int cb = kq - (kq / cbTot)*cbTot;

  bool isP = rb >= rbS;
  const half_t* A = isP ? A1 : A0;
  const half_t* B = isP ? B1 : B0;
  int K = isP ? K1 : K0;
  int row0 = (isP ? rb - rbS : rb) * 64;
  int col0 = cb * 128;
  int tid = threadIdx.x, lane = tid & 63, w = tid >> 6;
  int l15 = lane & 15, l4 = lane >> 4;
  int wr = (w >> 2) * 32, wc = (w & 3) * 32;

  const half_t* srcb[3];
  int ldso[3];
#pragma unroll
  for (int j = 0; j < 3; ++j) {
    int c = ((j*8 + w) << 6) + lane;
    const half_t* base;
    if (c < 512) {
      int r = c >> 3, kb = c & 7;
      base = A + (size_t)(row0 + r)*K + ((kb ^ (r & 7)) << 3);
    } else {
      int d = c - 512, r = d >> 3, kb = d & 7;
      base = B + (size_t)(col0 + r)*K + ((kb ^ (r & 7)) << 3);
    }
    srcb[j] = base;
    ldso[j] = c << 3;
  }

  f32x4 acc[2][2];
#pragma unroll
  for (int i = 0; i < 2; ++i)
#pragma unroll
    for (int j = 0; j < 2; ++j) acc[i][j] = (f32x4){0.f,0.f,0.f,0.f};

  int nk = K >> 6;
#define STAGEP(K0E, BUFP)  { half_t* _b = (BUFP); _Pragma("unroll") \
    for (int j = 0; j < 3; ++j) gl16(srcb[j] + (K0E), _b + ldso[j]); }

  STAGEP(0,   &sbuf[0][0]);
  STAGEP(64,  &sbuf[1][0]);
  STAGEP(128, &sbuf[2][0]);

  for (int k = 0; k < nk; ++k) {
    int rem = nk - 1 - k;
    if (rem >= 2)      asm volatile("s_waitcnt vmcnt(6)" ::: "memory");
    else if (rem == 1) asm volatile("s_waitcnt vmcnt(3)" ::: "memory");
    else               asm volatile("s_waitcnt vmcnt(0)" ::: "memory");
    __builtin_amdgcn_s_barrier();
    const half_t* cur = &sbuf[k % 3][0];
    const half_t* cB = cur + 4096;
#pragma unroll
    for (int kk = 0; kk < 2; ++kk) {
      f16x8 af[2], bq[2];
#pragma unroll
      for (int mi = 0; mi < 2; ++mi) {
        int r = wr + mi*16 + l15;
        int sb = (kk*4 + l4) ^ (r & 7);
        af[mi] = *(const f16x8*)&cur[r*64 + sb*8];
      }
#pragma unroll
      for (int ni = 0; ni < 2; ++ni) {
        int r = wc + ni*16 + l15;
        int sb = (kk*4 + l4) ^ (r & 7);
        bq[ni] = *(const f16x8*)&cB[r*64 + sb*8];
      }
#pragma unroll
      for (int mi = 0; mi < 2; ++mi)
#pragma unroll
        for (int ni = 0; ni < 2; ++ni)
          acc[mi][ni] = __builtin_amdgcn_mfma_f32_16x16x32_f16(af[mi], bq[ni], acc[mi][ni], 0, 0, 0);
    }
    __builtin_amdgcn_s_barrier();
    if (k + 3 < nk) STAGEP((k + 3) << 6, &sbuf[k % 3][0]);
  }
#undef STAGEP

  half_t* PxO = isP ? Px1 : Px0;
#pragma unroll
  for (int mi = 0; mi < 2; ++mi)
#pragma unroll
    for (int ni = 0; ni < 2; ++ni) {
      int colg = col0 + wc + ni*16 + l15;
      const float* bias = (colg < 256) ? (isP ? bz1 : bz0)
                        : (colg < 512) ? (isP ? br1 : br0)
                                       : (isP ? bh1 : bh0);
#pragma unroll
      for (int rg = 0; rg < 4; ++rg) {
        int grow = row0 + wr + mi*16 + l4*4 + rg;
        PxO[(size_t)grow*NPRE + colg] = (half_t)(acc[mi][ni][rg] + bias[colg & 255]);
      }
    }
}

// ---------------- fused recurrence: GEMM + node contraction + GRU epilogue ----------------
// Tile: M=32 (s: 1 b, 20 valid rows; p: 4 b's, 32 rows), N = NTAU*128 (cols ordered jc*NTAU+tau),
// K=256 in 8 BK=32 steps, double-buffered gl16 B-staging, A static in LDS.
// GATE 0 (JW=512, JB=4): jb<2 -> Z = sigmoid; jb>=2 -> gHf = f16(sig*H)
// GATE 1 (JW=256, JB=2): H = Z*H + (1-Z)*tanh ; write H fp32 + Hf f16
template<int GATE>
__global__ __launch_bounds__(512) void rec_k(
    const half_t* __restrict__ Asrc_s, const half_t* __restrict__ Asrc_p,
    const half_t* __restrict__ WH_s, const half_t* __restrict__ WH_p,
    const half_t* __restrict__ Px_s, const half_t* __restrict__ Px_p,
    const float* __restrict__ Mb_s, const float* __restrict__ Mb_p,
    const float* __restrict__ Hin, float* __restrict__ Z,
    half_t* __restrict__ Out_s, half_t* __restrict__ Out_p,
    float* __restrict__ Hout, int nSblk) {
  constexpr int JB = GATE ? 2 : 4;
  constexpr int JW = GATE ? 256 : 512;
  __shared__ __align__(16) half_t ring[2][20480];   // B dbuf: [col][32]
  __shared__ __align__(16) half_t Hl[32*264];
  __shared__ float Mbl[2000];
  half_t* Yt = &ring[0][0];                          // overlay after K-loop: [128 jc][100]

  int id = blockIdx.x, tid = threadIdx.x;
  int lane = tid & 63, w = tid >> 6;
  int l15 = lane & 15, l4 = lane >> 4;
  bool isP = id >= nSblk;
  int q = isP ? id - nSblk : id;
  int bb = q / JB, jb = q - bb*JB;     // s: bb = b ; p: bb = bg (4 b's)
  int NTAU = isP ? 3 : 5;
  int NCOL = NTAU << 7;
  int NW = NTAU << 4;
  int nld = NTAU;                      // gl16 per thread per stage (NCOL*4/512)
  const half_t* B = isP ? WH_p : WH_s;

  // ---- stage A rows + Mb into LDS ----
  if (!isP) {
    const half_t* src = Asrc_s + (size_t)bb*20*256;
    for (int c = tid; c < 640; c += 512) {
      int r = c >> 5, qq = c & 31;
      *(uint4*)&Hl[r*264 + qq*8] = *(const uint4*)&src[(size_t)r*256 + qq*8];
    }
    for (int i = tid; i < 2000; i += 512) Mbl[i] = Mb_s[i];
  } else {
    const half_t* src = Asrc_p + (size_t)bb*32*256;
    for (int c = tid; c < 1024; c += 512) {
      int r = c >> 5, qq = c & 31;
      *(uint4*)&Hl[r*264 + qq*8] = *(const uint4*)&src[(size_t)r*256 + qq*8];
    }
    for (int i = tid; i < 192; i += 512) Mbl[i] = Mb_p[i];
  }

  // ---- B staging sources (chunk c -> LDS col-row r, kchunk kb, pre-swizzled) ----
  const half_t* bsrc[5];
  int bdst[5];
#pragma unroll
  for (int j = 0; j < 5; ++j) {
    int c = j*512 + tid;
    int r = c >> 2, kb = c & 3;
    int jc = r / NTAU, tau = r - jc*NTAU;
    int gcol = tau*JW + (jb << 7) + jc;
    bsrc[j] = B + (size_t)gcol*256 + ((kb ^ (r & 3)) << 3);
    bdst[j] = c << 3;
  }

  // ---- A/B fragment addresses ----
  int ab[2];
#pragma unroll
  for (int mi = 0; mi < 2; ++mi) {
    int row = mi*16 + l15;
    int hr = isP ? row : (row < 20 ? row : 19);
    ab[mi] = hr*264 + l4*8;
  }
  int bboff[5];
#pragma unroll
  for (int ni = 0; ni < 5; ++ni) {
    int col = w*NW + ni*16 + l15;
    int cc = (ni < nld) ? col : 0;
    bboff[ni] = cc*32 + ((l4 ^ (cc & 3)) << 3);
  }

  f32x4 acc[2][5];
#pragma unroll
  for (int i = 0; i < 2; ++i)
#pragma unroll
    for (int j = 0; j < 5; ++j) acc[i][j] = (f32x4){0.f,0.f,0.f,0.f};

#define BSTAGE(K0E, BUFP) { half_t* _b = (BUFP); _Pragma("unroll") \
    for (int j = 0; j < 5; ++j) if (j < nld) gl16(bsrc[j] + (K0E), _b + bdst[j]); }

  BSTAGE(0, &ring[0][0]);
  __syncthreads();                      // Hl/Mbl ready

  for (int k = 0; k < 8; ++k) {
    if (k < 7) {
      BSTAGE((k + 1) << 5, &ring[(k + 1) & 1][0]);
      if (!isP) asm volatile("s_waitcnt vmcnt(5)" ::: "memory");
      else      asm volatile("s_waitcnt vmcnt(3)" ::: "memory");
    } else {
      asm volatile("s_waitcnt vmcnt(0)" ::: "memory");
    }
    __builtin_amdgcn_s_barrier();
    const half_t* cur = &ring[k & 1][0];
    f16x8 af[2], bq[5];
#pragma unroll
    for (int mi = 0; mi < 2; ++mi) af[mi] = *(const f16x8*)&Hl[ab[mi] + (k << 5)];
#pragma unroll
    for (int ni = 0; ni < 5; ++ni) if (ni < nld) bq[ni] = *(const f16x8*)&cur[bboff[ni]];
#pragma unroll
    for (int mi = 0; mi < 2; ++mi)
#pragma unroll
      for (int ni = 0; ni < 5; ++ni) if (ni < nld)
        acc[mi][ni] = __builtin_amdgcn_mfma_f32_16x16x32_f16(af[mi], bq[ni], acc[mi][ni], 0, 0, 0);
    __builtin_amdgcn_s_barrier();
  }
#undef BSTAGE

  // ---- dump Y tile (fp16) into freed ring LDS: Yt[jc][ri], stride 100 ----
#pragma unroll
  for (int ni = 0; ni < 5; ++ni) if (ni < nld) {
    int col = w*NW + ni*16 + l15;
    int jc = col / NTAU, tau = col - jc*NTAU;
#pragma unroll
    for (int mi = 0; mi < 2; ++mi) {
#pragma unroll
      for (int rg = 0; rg < 4; ++rg) {
        int r = mi*16 + l4*4 + rg;
        if (!isP) {
          if (r < 20) Yt[jc*100 + r*5 + tau] = (half_t)acc[mi][ni][rg];
        } else {
          Yt[jc*100 + (r >> 3)*24 + (r & 7)*3 + tau] = (half_t)acc[mi][ni][rg];
        }
      }
    }
  }
  __syncthreads();

  // ---- contraction + gate epilogue ----
  const half_t* Px = isP ? Px_p : Px_s;
  constexpr int PXOFF = GATE ? 512 : 0;
  if (!isP) {
    int b = bb;
    for (int o = tid; o < 20*128; o += 512) {
      int n = o >> 7, jc = o & 127;
      const float* mr = Mbl + n*100;
      const half_t* yc = Yt + jc*100;
      float p = 0.f;
#pragma unroll
      for (int g = 0; g < 25; ++g) {
        union { uint2 qv; half_t u[4]; } yy;
        yy.qv = *(const uint2*)&yc[g*4];
#pragma unroll
        for (int e = 0; e < 4; ++e) p += mr[g*4 + e]*(float)yy.u[e];
      }
      int colg = (jb << 7) + jc;
      p += (float)Px[((size_t)b*20 + n)*NPRE + PXOFF + colg];
      size_t hrow = (size_t)b*NN + n;
      if constexpr (GATE == 0) {
        if (jb < 2) {
          Z[hrow*256 + colg] = 1.f/(1.f + expf(-p));
        } else {
          int f = colg - 256;
          float gh = Hin[hrow*256 + f]/(1.f + expf(-p));
          Out_s[((size_t)b*20 + n)*256 + f] = (half_t)gh;
        }
      } else {
        size_t hidx = hrow*256 + colg;
        float ht = tanhf(p);
        float z = Z[hidx];
        float hn = z*Hin[hidx] + (1.f - z)*ht;
        Hout[hidx] = hn;
        Out_s[((size_t)b*20 + n)*256 + colg] = (half_t)hn;
      }
    }
  } else {
    for (int o = tid; o < 4*8*128; o += 512) {
      int bq = o >> 10, n = (o >> 7) & 7, jc = o & 127;
      int b = bb*4 + bq;
      const float* mr = Mbl + n*24;
      const half_t* yc = Yt + jc*100 + bq*24;
      float p = 0.f;
#pragma unroll
      for (int g = 0; g < 6; ++g) {
        union { uint2 qv; half_t u[4]; } yy;
        yy.qv = *(const uint2*)&yc[g*4];
#pragma unroll
        for (int e = 0; e < 4; ++e) p += mr[g*4 + e]*(float)yy.u[e];
      }
      int colg = (jb << 7) + jc;
      p += (float)Px[((size_t)b*8 + n)*NPRE + PXOFF + colg];
      size_t hrow = (size_t)b*NN + NSN + n;
      if constexpr (GATE == 0) {
        if (jb < 2) {
          Z[hrow*256 + colg] = 1.f/(1.f + expf(-p));
        } else {
          int f = colg - 256;
          float gh = Hin[hrow*256 + f]/(1.f + expf(-p));
          Out_p[((size_t)b*8 + n)*256 + f] = (half_t)gh;
        }
      } else {
        size_t hidx = hrow*256 + colg;
        float ht = tanhf(p);
        float z = Z[hidx];
        float hn = z*Hin[hidx] + (1.f - z)*ht;
        Hout[hidx] = hn;
        Out_p[((size_t)b*8 + n)*256 + colg] = (half_t)hn;
      }
    }
  }
}

// ---------------- readout ----------------
__global__ __launch_bounds__(256) void readout_k(const float* __restrict__ H, const float* __restrict__ W_ro,
                                                 const float* __restrict__ b_ro, const float* __restrict__ W_ag,
                                                 const float* __restrict__ b_ag, float* __restrict__ out) {
  __shared__ float red[256];
  __shared__ float o1[NN];
  int b = blockIdx.x, tid = threadIdx.x;
  float wro = W_ro[tid];
  for (int n = 0; n < NN; ++n) {
    red[tid] = H[((size_t)b*NN + n)*256 + tid] * wro;
    __syncthreads();
    for (int s = 128; s > 0; s >>= 1) { if (tid < s) red[tid] += red[tid+s]; __syncthreads(); }
    if (tid == 0) o1[n] = red[0] + b_ro[0];
    __syncthreads();
  }
  if (tid < 5) {
    float s = b_ag[tid];
    for (int n = 0; n < NN; ++n) s += o1[n] * W_ag[n*5 + tid];
    out[b*5 + tid] = s;
  }
}

// ---------------- host ----------------
extern "C" void kernel_launch(void* const* d_in, const int* in_sizes, int n_in,
                              void* d_out, int out_size, void* d_ws, size_t ws_size,
                              hipStream_t stream) {
  const float* xdis = (const float*)d_in[0];
  const float* xpre = (const float*)d_in[1];
  const int*   ei_s = (const int*)d_in[2];
  const int*   ei_p = (const int*)d_in[3];
  const float* ew_s = (const float*)d_in[4];
  const float* ew_p = (const float*)d_in[5];
  const float* Wz_s = (const float*)d_in[6];
  const float* bz_s = (const float*)d_in[7];
  const float* Wr_s = (const float*)d_in[8];
  const float* br_s = (const float*)d_in[9];
  const float* Wh_s = (const float*)d_in[10];
  const float* bh_s = (const float*)d_in[11];
  const float* Wz_p = (const float*)d_in[12];
  const float* bz_p = (const float*)d_in[13];
  const float* Wr_p = (const float*)d_in[14];
  const float* br_p = (const float*)d_in[15];
  const float* Wh_p = (const float*)d_in[16];
  const float* bh_p = (const float*)d_in[17];
  const float* W_ro = (const float*)d_in[18];
  const float* b_ro = (const float*)d_in[19];
  const float* W_ag = (const float*)d_in[20];
  const float* b_ag = (const float*)d_in[21];
  float* out = (float*)d_out;
  (void)in_sizes; (void)n_in; (void)out_size; (void)ws_size;

  char* w = (char*)d_ws;
  size_t off = 0;
  auto alloc = [&](size_t bytes) { void* p = w + off; off = (off + bytes + 255) & ~(size_t)255; return p; };

  const size_t rowsXs = (size_t)TCH*NB*NSN, rowsXp = (size_t)TCH*NB*NPN;

  float* Ms_s = (float*)alloc(4*NSN*NSN*sizeof(float));
  float* Ms_p = (float*)alloc(2*NPN*NPN*sizeof(float));
  float* Mbig_s = (float*)alloc(NSN*100*sizeof(float));
  float* Mbig_p = (float*)alloc(NPN*24*sizeof(float));
  half_t* WX_s = (half_t*)alloc((size_t)768*KHS*2);
  half_t* WX_p = (half_t*)alloc((size_t)768*KHP*2);
  half_t* WHzr_s = (half_t*)alloc((size_t)2560*256*2);
  half_t* WHh_s  = (half_t*)alloc((size_t)1280*256*2);
  half_t* WHzr_p = (half_t*)alloc((size_t)1536*256*2);
  half_t* WHh_p  = (half_t*)alloc((size_t)768*256*2);
  half_t* XT_s = (half_t*)alloc(rowsXs*KHS*2);
  half_t* XT_p = (half_t*)alloc(rowsXp*KHP*2);
  half_t* Px_s = (half_t*)alloc((size_t)TT*NB*NSN*NPRE*2);
  half_t* Px_p = (half_t*)alloc((size_t)TT*NB*NPN*NPRE*2);
  float* H  = (float*)alloc((size_t)NB*NN*256*4);
  float* Z  = (float*)alloc((size_t)NB*NN*256*4);
  half_t* Hf  = (half_t*)alloc((size_t)NB*NN*256*2);
  half_t* gHf = (half_t*)alloc((size_t)NB*NN*256*2);
  half_t* Hf_s = Hf,  * Hf_p = Hf + (size_t)NB*NSN*256;
  half_t* gHf_s = gHf, * gHf_p = gHf + (size_t)NB*NSN*256;

  graph_build<<<1, 64, 0, stream>>>(ei_s, ew_s, ei_p, ew_p, Ms_s, Ms_p, Mbig_s, Mbig_p);
  prep_w<<<1024, 256, 0, stream>>>(Wz_s, Wr_s, Wh_s, Wz_p, Wr_p, Wh_p,
                                   WX_s, WX_p, WHzr_s, WHh_s, WHzr_p, WHh_p);
  const long nH = (long)NB*NN*256;
  zero_f<<<(nH + 255)/256, 256, 0, stream>>>(H, nH);
  zero_f<<<(nH/2 + 255)/256, 256, 0, stream>>>((float*)Hf, nH/2);

  // ---- precompute Px ----
  for (int t0 = 0; t0 < TT; t0 += TCH) {
    chebx<<<2*NB*TCH, 256, 0, stream>>>(xdis, xpre, Ms_s, Ms_p, XT_s, XT_p, t0);
    gemm_pre<<<224*6, 512, 0, stream>>>(
        XT_s, WX_s, KHS, 160, 6,
        XT_p, WX_p, KHP,
        Px_s + (size_t)t0*NB*NSN*NPRE, Px_p + (size_t)t0*NB*NPN*NPRE,
        bz_s, br_s, bh_s, bz_p, br_p, bh_p);
  }

  // ---- recurrence: 2 fused dispatches per step ----
  for (int t = 0; t < TT; ++t) {
    const half_t* PxS = Px_s + (size_t)t*NB*NSN*NPRE;
    const half_t* PxP = Px_p + (size_t)t*NB*NPN*NPRE;
    rec_k<0><<<NB*4 + 32*4, 512, 0, stream>>>(
        Hf_s, Hf_p, WHzr_s, WHzr_p, PxS, PxP, Mbig_s, Mbig_p,
        H, Z, gHf_s, gHf_p, nullptr, NB*4);
    rec_k<1><<<NB*2 + 32*2, 512, 0, stream>>>(
        gHf_s, gHf_p, WHh_s, WHh_p, PxS, PxP, Mbig_s, Mbig_p,
        H, Z, Hf_s, Hf_p, H, NB*2);
  }
  readout_k<<<NB, 256, 0, stream>>>(H, W_ro, b_ro, W_ag, b_ag, out);
}

// Round 11
// 2268.219 us; speedup vs baseline: 1.0226x; 1.0226x over previous
//
#include <hip/hip_runtime.h>
#include <stdint.h>

#define NSN 20
#define NPN 8
#define NB 128
#define TT 24
#define NN 28
#define ES 100
#define EP 32
#define KHS 1280
#define KHP 768
#define NPRE 768
#define TCH 4

typedef _Float16 half_t;
typedef __attribute__((ext_vector_type(8))) _Float16 f16x8;
typedef __attribute__((ext_vector_type(4))) float f32x4;

__device__ __forceinline__ void gl16(const half_t* g, half_t* l) {
  __builtin_amdgcn_global_load_lds((const __attribute__((address_space(1))) void*)g,
                                   (__attribute__((address_space(3))) void*)l, 16, 0, 0);
}

// ---------------- graph build (edges staged in LDS) ----------------
__global__ void graph_build(const int* __restrict__ ei_s, const float* __restrict__ ew_s,
                            const int* __restrict__ ei_p, const float* __restrict__ ew_p,
                            float* __restrict__ Ms_s, float* __restrict__ Ms_p,
                            float* __restrict__ Mbig_s, float* __restrict__ Mbig_p) {
  __shared__ float Ao[NSN*NSN], Aiw[NSN*NSN], dgo[NSN], dgi[NSN];
  __shared__ float T2o[NSN*NSN], T2i[NSN*NSN];
  __shared__ float Aop[NPN*NPN], Aip[NPN*NPN], dgop[NPN], dgip[NPN];
  __shared__ int eis[2*ES]; __shared__ float ews[ES];
  __shared__ int eip[2*EP]; __shared__ float ewp[EP];
  int tid = threadIdx.x;
  for (int i = tid; i < 2*ES; i += blockDim.x) eis[i] = ei_s[i];
  for (int i = tid; i < ES; i += blockDim.x) ews[i] = ew_s[i];
  for (int i = tid; i < 2*EP; i += blockDim.x) eip[i] = ei_p[i];
  for (int i = tid; i < EP; i += blockDim.x) ewp[i] = ew_p[i];
  for (int i = tid; i < NSN*NSN; i += blockDim.x) { Ao[i] = 0.f; Aiw[i] = 0.f; }
  for (int i = tid; i < NPN*NPN; i += blockDim.x) { Aop[i] = 0.f; Aip[i] = 0.f; }
  if (tid < NSN) { dgo[tid] = 0.f; dgi[tid] = 0.f; }
  if (tid < NPN) { dgop[tid] = 0.f; dgip[tid] = 0.f; }
  __syncthreads();
  if (tid == 0) {
    for (int e = 0; e < ES; ++e) { int r = eis[e], c = eis[ES+e]; float w = ews[e]; dgo[r] += w; dgi[c] += w; }
    for (int e = 0; e < ES; ++e) { int r = eis[e], c = eis[ES+e]; Ao[c*NSN+r] += 1.f/dgo[r]; Aiw[c*NSN+r] += 1.f/dgi[r]; }
  }
  if (tid == 1) {
    for (int e = 0; e < EP; ++e) { int r = eip[e], c = eip[EP+e]; float w = ewp[e]; dgop[r] += w; dgip[c] += w; }
    for (int e = 0; e < EP; ++e) { int r = eip[e], c = eip[EP+e]; Aop[c*NPN+r] += 1.f/dgop[r]; Aip[c*NPN+r] += 1.f/dgip[r]; }
  }
  __syncthreads();
  for (int i = tid; i < NSN*NSN; i += blockDim.x) {
    int r = i / NSN, c = i % NSN;
    float so = 0.f, si = 0.f;
    for (int k = 0; k < NSN; ++k) { so += Ao[r*NSN+k]*Ao[k*NSN+c]; si += Aiw[r*NSN+k]*Aiw[k*NSN+c]; }
    float t2o = 2.f*so - (r==c ? 1.f : 0.f);
    float t2i = 2.f*si - (r==c ? 1.f : 0.f);
    T2o[i] = t2o; T2i[i] = t2i;
    Ms_s[0*NSN*NSN + i] = Ao[i];
    Ms_s[1*NSN*NSN + i] = Aiw[i];
    Ms_s[2*NSN*NSN + i] = t2o;
    Ms_s[3*NSN*NSN + i] = t2i;
  }
  for (int i = tid; i < NPN*NPN; i += blockDim.x) {
    Ms_p[0*NPN*NPN + i] = Aop[i];
    Ms_p[1*NPN*NPN + i] = Aip[i];
  }
  __syncthreads();
  for (int i = tid; i < NSN*NSN*5; i += blockDim.x) {
    int n = i / 100, s = i % 100, r = s / 5, tau = s % 5;
    float v;
    if (tau == 0) v = (n == r) ? 1.f : 0.f;
    else if (tau == 1) v = Ao[n*NSN + r];
    else if (tau == 2) v = Aiw[n*NSN + r];
    else if (tau == 3) v = T2o[n*NSN + r];
    else               v = T2i[n*NSN + r];
    Mbig_s[i] = v;
  }
  for (int i = tid; i < NPN*NPN*3; i += blockDim.x) {
    int n = i / 24, s = i % 24, r = s / 3, tau = s % 3;
    float v;
    if (tau == 0) v = (n == r) ? 1.f : 0.f;
    else if (tau == 1) v = Aop[n*NPN + r];
    else               v = Aip[n*NPN + r];
    Mbig_p[i] = v;
  }
}

// ---------------- weight prep (fp16) ----------------
__device__ __forceinline__ float wsrc(const float* W, int Kdim, int tau, int i, int jj) {
  if (tau == 0) return W[(size_t)(0*Kdim+0)*512*256 + (size_t)i*256 + jj]
                     + W[(size_t)(1*Kdim+0)*512*256 + (size_t)i*256 + jj];
  int dir = (tau - 1) & 1;
  int k = (tau + 1) >> 1;
  return W[(size_t)(dir*Kdim + k)*512*256 + (size_t)i*256 + jj];
}

__global__ void prep_w(const float* __restrict__ Wz_s, const float* __restrict__ Wr_s, const float* __restrict__ Wh_s,
                       const float* __restrict__ Wz_p, const float* __restrict__ Wr_p, const float* __restrict__ Wh_p,
                       half_t* __restrict__ WX_s, half_t* __restrict__ WX_p,
                       half_t* __restrict__ WHzr_s, half_t* __restrict__ WHh_s,
                       half_t* __restrict__ WHzr_p, half_t* __restrict__ WHh_p) {
  const long c0 = (long)768*KHS;
  const long c1 = c0 + (long)768*KHP;
  const long c2 = c1 + (long)2560*256;
  const long c3 = c2 + (long)1280*256;
  const long c4 = c3 + (long)1536*256;
  const long c5 = c4 + (long)768*256;
  for (long idx = (long)blockIdx.x*256 + threadIdx.x; idx < c5; idx += (long)gridDim.x*256) {
    if (idx < c0) {
      long x = idx; int j = (int)(x / KHS), c = (int)(x % KHS); int tau = c >> 8;
      const float* W = (j < 256) ? Wz_s : (j < 512) ? Wr_s : Wh_s;
      WX_s[x] = (half_t)wsrc(W, 3, tau, c & 255, j & 255);
    } else if (idx < c1) {
      long x = idx - c0; int j = (int)(x / KHP), c = (int)(x % KHP); int tau = c >> 8;
      const float* W = (j < 256) ? Wz_p : (j < 512) ? Wr_p : Wh_p;
      WX_p[x] = (half_t)wsrc(W, 2, tau, c & 255, j & 255);
    } else if (idx < c2) {
      long x = idx - c1; int cc = (int)(x >> 8), f = (int)(x & 255);
      int tau = cc / 512, j = cc % 512;
      const float* W = (j < 256) ? Wz_s : Wr_s;
      WHzr_s[(size_t)cc*256 + f] = (half_t)wsrc(W, 3, tau, 256 + f, j & 255);
    } else if (idx < c3) {
      long x = idx - c2; int cc = (int)(x >> 8), f = (int)(x & 255);
      int tau = cc >> 8, j = cc & 255;
      WHh_s[(size_t)cc*256 + f] = (half_t)wsrc(Wh_s, 3, tau, 256 + f, j);
    } else if (idx < c4) {
      long x = idx - c3; int cc = (int)(x >> 8), f = (int)(x & 255);
      int tau = cc / 512, j = cc % 512;
      const float* W = (j < 256) ? Wz_p : Wr_p;
      WHzr_p[(size_t)cc*256 + f] = (half_t)wsrc(W, 2, tau, 256 + f, j & 255);
    } else {
      long x = idx - c4; int cc = (int)(x >> 8), f = (int)(x & 255);
      int tau = cc >> 8, j = cc & 255;
      WHh_p[(size_t)cc*256 + f] = (half_t)wsrc(Wh_p, 2, tau, 256 + f, j);
    }
  }
}

__global__ void zero_f(float* p, long n) {
  long i = (long)blockIdx.x*256 + threadIdx.x;
  if (i < n) p[i] = 0.f;
}

// ---------------- cheb expansion of X (precompute A), fp16 ----------------
__global__ __launch_bounds__(256) void chebx(const float* __restrict__ xdis, const float* __restrict__ xpre,
                                             const float* __restrict__ Ms_s, const float* __restrict__ Ms_p,
                                             half_t* __restrict__ XTs, half_t* __restrict__ XTp, int t0) {
  __shared__ float Xc[NSN*256];
  __shared__ float Ml[4*NSN*NSN];
  int bb = blockIdx.x, tid = threadIdx.x;
  bool isP = bb >= NB*TCH;
  int q = isP ? bb - NB*TCH : bb;
  int b = q % NB, tp = q / NB;
  int N = isP ? NPN : NSN, nt = isP ? 3 : 5, KX = nt << 8;
  const float* X = isP ? (xpre + (size_t)(b*TT + t0 + tp)*NPN*256)
                       : (xdis + (size_t)(b*TT + t0 + tp)*NSN*256);
  for (int i = tid; i < N*64; i += 256) ((float4*)Xc)[i] = ((const float4*)X)[i];
  int nm = (nt-1)*N*N;
  const float* Msrc = isP ? Ms_p : Ms_s;
  for (int i = tid; i < nm; i += 256) Ml[i] = Msrc[i];
  __syncthreads();
  half_t* XT = isP ? XTp : XTs;
  size_t rowbase = (size_t)(tp*NB + b)*N;
  int kc8 = KX >> 3, nch = N * kc8;
  for (int i = tid; i < nch; i += 256) {
    int n = i / kc8, c8 = i - n*kc8;
    int tau = c8 >> 5, f0 = (c8 & 31) << 3;
    float v[8];
    if (tau == 0) {
      const float* xr0 = Xc + n*256 + f0;
#pragma unroll
      for (int j = 0; j < 8; ++j) v[j] = xr0[j];
    } else {
      const float* M = Ml + (tau-1)*N*N + n*N;
#pragma unroll
      for (int j = 0; j < 8; ++j) v[j] = 0.f;
      for (int r = 0; r < N; ++r) {
        float m = M[r];
        const float* xr = Xc + r*256 + f0;
#pragma unroll
        for (int j = 0; j < 8; ++j) v[j] += m*xr[j];
      }
    }
    union { uint4 q; half_t u[8]; } hv;
#pragma unroll
    for (int j = 0; j < 8; ++j) hv.u[j] = (half_t)v[j];
    *(uint4*)(XT + (rowbase + n)*(size_t)KX + ((size_t)c8 << 3)) = hv.q;
  }
}

// ---------------- precompute GEMM (R8, unchanged) ----------------
__global__ __launch_bounds__(512) void gemm_pre(
    const half_t* __restrict__ A0, const half_t* __restrict__ B0, int K0,
    int rbS, int cbTot,
    const half_t* __restrict__ A1, const half_t* __restrict__ B1, int K1,
    half_t* __restrict__ Px0, half_t* __restrict__ Px1,
    const float* __restrict__ bz0, const float* __restrict__ br0, const float* __restrict__ bh0,
    const float* __restrict__ bz1, const float* __restrict__ br1, const float* __restrict__ bh1) {
  __shared__ __align__(16) half_t sbuf[3][12288];
  int id = blockIdx.x;
  int xx = id & 7, kq = id >> 3;
  int rbTot8 = (gridDim.x / cbTot) >> 3;
  int rb = xx*rbTot8 + kq / cbTot;
  int cb = kq - (kq / cbTot)*cbTot;

  bool isP = rb >= rbS;
  const half_t* A = isP ? A1 : A0;
  const half_t* B = isP ? B1 : B0;
  int K = isP ? K1 : K0;
  int row0 = (isP ? rb - rbS : rb) * 64;
  int col0 = cb * 128;
  int tid = threadIdx.x, lane = tid & 63, w = tid >> 6;
  int l15 = lane & 15, l4 = lane >> 4;
  int wr = (w >> 2) * 32, wc = (w & 3) * 32;

  const half_t* srcb[3];
  int ldso[3];
#pragma unroll
  for (int j = 0; j < 3; ++j) {
    int c = ((j*8 + w) << 6) + lane;
    const half_t* base;
    if (c < 512) {
      int r = c >> 3, kb = c & 7;
      base = A + (size_t)(row0 + r)*K + ((kb ^ (r & 7)) << 3);
    } else {
      int d = c - 512, r = d >> 3, kb = d & 7;
      base = B + (size_t)(col0 + r)*K + ((kb ^ (r & 7)) << 3);
    }
    srcb[j] = base;
    ldso[j] = c << 3;
  }

  f32x4 acc[2][2];
#pragma unroll
  for (int i = 0; i < 2; ++i)
#pragma unroll
    for (int j = 0; j < 2; ++j) acc[i][j] = (f32x4){0.f,0.f,0.f,0.f};

  int nk = K >> 6;
#define STAGEP(K0E, BUFP)  { half_t* _b = (BUFP); _Pragma("unroll") \
    for (int j = 0; j < 3; ++j) gl16(srcb[j] + (K0E), _b + ldso[j]); }

  STAGEP(0,   &sbuf[0][0]);
  STAGEP(64,  &sbuf[1][0]);
  STAGEP(128, &sbuf[2][0]);

  for (int k = 0; k < nk; ++k) {
    int rem = nk - 1 - k;
    if (rem >= 2)      asm volatile("s_waitcnt vmcnt(6)" ::: "memory");
    else if (rem == 1) asm volatile("s_waitcnt vmcnt(3)" ::: "memory");
    else               asm volatile("s_waitcnt vmcnt(0)" ::: "memory");
    __builtin_amdgcn_s_barrier();
    const half_t* cur = &sbuf[k % 3][0];
    const half_t* cB = cur + 4096;
#pragma unroll
    for (int kk = 0; kk < 2; ++kk) {
      f16x8 af[2], bq[2];
#pragma unroll
      for (int mi = 0; mi < 2; ++mi) {
        int r = wr + mi*16 + l15;
        int sb = (kk*4 + l4) ^ (r & 7);
        af[mi] = *(const f16x8*)&cur[r*64 + sb*8];
      }
#pragma unroll
      for (int ni = 0; ni < 2; ++ni) {
        int r = wc + ni*16 + l15;
        int sb = (kk*4 + l4) ^ (r & 7);
        bq[ni] = *(const f16x8*)&cB[r*64 + sb*8];
      }
#pragma unroll
      for (int mi = 0; mi < 2; ++mi)
#pragma unroll
        for (int ni = 0; ni < 2; ++ni)
          acc[mi][ni] = __builtin_amdgcn_mfma_f32_16x16x32_f16(af[mi], bq[ni], acc[mi][ni], 0, 0, 0);
    }
    __builtin_amdgcn_s_barrier();
    if (k + 3 < nk) STAGEP((k + 3) << 6, &sbuf[k % 3][0]);
  }
#undef STAGEP

  half_t* PxO = isP ? Px1 : Px0;
#pragma unroll
  for (int mi = 0; mi < 2; ++mi)
#pragma unroll
    for (int ni = 0; ni < 2; ++ni) {
      int colg = col0 + wc + ni*16 + l15;
      const float* bias = (colg < 256) ? (isP ? bz1 : bz0)
                        : (colg < 512) ? (isP ? br1 : br0)
                                       : (isP ? bh1 : bh0);
#pragma unroll
      for (int rg = 0; rg < 4; ++rg) {
        int grow = row0 + wr + mi*16 + l4*4 + rg;
        PxO[(size_t)grow*NPRE + colg] = (half_t)(acc[mi][ni][rg] + bias[colg & 255]);
      }
    }
}

// ---------------- fused recurrence v2: A in LDS (kb-major), B from L2 to regs, f32 Yt ----------------
// s-block: 1 batch (20 rows, padded to 32); p-block: 4 batches (32 rows).
// Cols: NTAU tau-slices of 128 jc (NCOL = 640 s / 384 p). K=256 in 8 steps of 32; no K-loop barriers.
// GATE 0: colg<256 -> Z = sigmoid; else gHf = f16(sig*H).   GATE 1: H = Z*H+(1-Z)*tanh; write H + Hf.
template<int GATE>
__global__ __launch_bounds__(512, 4) void rec2_k(
    const half_t* __restrict__ Af_s, const half_t* __restrict__ Af_p,
    const half_t* __restrict__ WH_s, const half_t* __restrict__ WH_p,
    const half_t* __restrict__ Px_s, const half_t* __restrict__ Px_p,
    const float* __restrict__ Mb_s, const float* __restrict__ Mb_p,
    const float* __restrict__ Hin, float* __restrict__ Z,
    half_t* __restrict__ Out_s, half_t* __restrict__ Out_p,
    float* __restrict__ Hout, int nSblk) {
  constexpr int JB = GATE ? 2 : 4;
  constexpr int JW = GATE ? 256 : 512;
  __shared__ __align__(16) half_t Hl[8192];     // [kb 0..31][row 0..31][8] = 16KB
  __shared__ __align__(16) float Yt[12800];     // [sidx][128 jc]  (s:100, p:96 sidx)
  __shared__ float Mbl[2000];
  int id = blockIdx.x, tid = threadIdx.x;
  int lane = tid & 63, w = tid >> 6;
  int l15 = lane & 15, l4 = lane >> 4;
  bool isP = id >= nSblk;
  int q = isP ? id - nSblk : id;
  int bb = q / JB, jb = q - bb*JB;
  int NTAU = isP ? 3 : 5;
  int nld = NTAU;
  int WCOL = NTAU << 4;        // cols per wave
  const half_t* Asrc = isP ? (Af_p + (size_t)bb*32*256) : (Af_s + (size_t)bb*20*256);
  const half_t* B = isP ? WH_p : WH_s;

  // stage A: chunk c = kb*32 + row ; LDS half-off = c*8 ; src = row*256 + kb*8
  for (int c = tid; c < 1024; c += 512)
    gl16(Asrc + ((size_t)(c & 31)*256 + (c >> 5)*8), &Hl[c << 3]);
  int nmb = isP ? 192 : 2000;
  const float* Mbg = isP ? Mb_p : Mb_s;
  for (int i = tid; i < nmb; i += 512) Mbl[i] = Mbg[i];

  // B pointers (per-ni col -> global col)
  const half_t* Bbase[5];
#pragma unroll
  for (int ni = 0; ni < 5; ++ni) {
    int col = w*WCOL + ni*16 + l15;
    int cc = (ni < nld) ? col : 0;
    int tau = cc >> 7, jc = cc & 127;
    Bbase[ni] = B + (size_t)(tau*JW + jb*128 + jc)*256 + l4*8;
  }

  f32x4 acc[2][5];
#pragma unroll
  for (int i = 0; i < 2; ++i)
#pragma unroll
    for (int j = 0; j < 5; ++j) acc[i][j] = (f32x4){0.f,0.f,0.f,0.f};

  f16x8 bq[5];
#pragma unroll
  for (int ni = 0; ni < 5; ++ni) if (ni < nld) bq[ni] = *(const f16x8*)(Bbase[ni]);
  __syncthreads();   // A + Mb staged (syncthreads drains vmcnt)

#pragma unroll
  for (int k = 0; k < 8; ++k) {
    f16x8 bn[5];
    if (k < 7) {
#pragma unroll
      for (int ni = 0; ni < 5; ++ni) if (ni < nld) bn[ni] = *(const f16x8*)(Bbase[ni] + ((k + 1) << 5));
    }
    f16x8 af[2];
#pragma unroll
    for (int mi = 0; mi < 2; ++mi)
      af[mi] = *(const f16x8*)&Hl[((k*4 + l4) << 8) + ((mi*16 + l15) << 3)];
#pragma unroll
    for (int mi = 0; mi < 2; ++mi)
#pragma unroll
      for (int ni = 0; ni < 5; ++ni) if (ni < nld)
        acc[mi][ni] = __builtin_amdgcn_mfma_f32_16x16x32_f16(af[mi], bq[ni], acc[mi][ni], 0, 0, 0);
    if (k < 7) {
#pragma unroll
      for (int ni = 0; ni < 5; ++ni) bq[ni] = bn[ni];
    }
  }

  // dump Y (f32) -> Yt[sidx][jc] ; conflict-free (consecutive jc per 16 lanes)
#pragma unroll
  for (int mi = 0; mi < 2; ++mi)
#pragma unroll
    for (int ni = 0; ni < 5; ++ni) if (ni < nld) {
      int col = w*WCOL + ni*16 + l15;
      int tau = col >> 7, jc = col & 127;
#pragma unroll
      for (int rg = 0; rg < 4; ++rg) {
        int r = mi*16 + l4*4 + rg;
        if (!isP) {
          if (r < 20) Yt[(r*5 + tau)*128 + jc] = acc[mi][ni][rg];
        } else {
          Yt[(((r >> 3)*8 + (r & 7))*3 + tau)*128 + jc] = acc[mi][ni][rg];
        }
      }
    }
  __syncthreads();

  // contraction + gate epilogue
  const half_t* Px = isP ? Px_p : Px_s;
  constexpr int PXOFF = GATE ? 512 : 0;
  int hoff = isP ? NSN : 0;
  if (!isP) {
    int b = bb;
    for (int o = tid; o < 2560; o += 512) {
      int n = o >> 7, jc = o & 127;
      const float* mr = Mbl + n*100;
      float p = 0.f;
#pragma unroll 4
      for (int s = 0; s < 100; ++s) p += mr[s] * Yt[(s << 7) + jc];
      int colg = (jb << 7) + jc;
      p += (float)Px[((size_t)b*20 + n)*NPRE + PXOFF + colg];
      size_t hrow = (size_t)b*NN + n;
      if constexpr (GATE == 0) {
        if (colg < 256) {
          Z[hrow*256 + colg] = 1.f/(1.f + expf(-p));
        } else {
          int f = colg - 256;
          float gh = Hin[hrow*256 + f]/(1.f + expf(-p));
          Out_s[((size_t)b*20 + n)*256 + f] = (half_t)gh;
        }
      } else {
        size_t hidx = hrow*256 + colg;
        float ht = tanhf(p);
        float z = Z[hidx];
        float hn = z*Hin[hidx] + (1.f - z)*ht;
        Hout[hidx] = hn;
        Out_s[((size_t)b*20 + n)*256 + colg] = (half_t)hn;
      }
    }
  } else {
    for (int o = tid; o < 4096; o += 512) {
      int bq4 = o >> 10, n = (o >> 7) & 7, jc = o & 127;
      int b = bb*4 + bq4;
      const float* mr = Mbl + n*24;
      const float* yc = Yt + (bq4*24 << 7);
      float p = 0.f;
#pragma unroll 4
      for (int s = 0; s < 24; ++s) p += mr[s] * yc[(s << 7) + jc];
      int colg = (jb << 7) + jc;
      p += (float)Px[((size_t)b*8 + n)*NPRE + PXOFF + colg];
      size_t hrow = (size_t)b*NN + hoff + n;
      if constexpr (GATE == 0) {
        if (colg < 256) {
          Z[hrow*256 + colg] = 1.f/(1.f + expf(-p));
        } else {
          int f = colg - 256;
          float gh = Hin[hrow*256 + f]/(1.f + expf(-p));
          Out_p[((size_t)b*8 + n)*256 + f] = (half_t)gh;
        }
      } else {
        size_t hidx = hrow*256 + colg;
        float ht = tanhf(p);
        float z = Z[hidx];
        float hn = z*Hin[hidx] + (1.f - z)*ht;
        Hout[hidx] = hn;
        Out_p[((size_t)b*8 + n)*256 + colg] = (half_t)hn;
      }
    }
  }
}

// ---------------- readout ----------------
__global__ __launch_bounds__(256) void readout_k(const float* __restrict__ H, const float* __restrict__ W_ro,
                                                 const float* __restrict__ b_ro, const float* __restrict__ W_ag,
                                                 const float* __restrict__ b_ag, float* __restrict__ out) {
  __shared__ float red[256];
  __shared__ float o1[NN];
  int b = blockIdx.x, tid = threadIdx.x;
  float wro = W_ro[tid];
  for (int n = 0; n < NN; ++n) {
    red[tid] = H[((size_t)b*NN + n)*256 + tid] * wro;
    __syncthreads();
    for (int s = 128; s > 0; s >>= 1) { if (tid < s) red[tid] += red[tid+s]; __syncthreads(); }
    if (tid == 0) o1[n] = red[0] + b_ro[0];
    __syncthreads();
  }
  if (tid < 5) {
    float s = b_ag[tid];
    for (int n = 0; n < NN; ++n) s += o1[n] * W_ag[n*5 + tid];
    out[b*5 + tid] = s;
  }
}

// ---------------- host ----------------
extern "C" void kernel_launch(void* const* d_in, const int* in_sizes, int n_in,
                              void* d_out, int out_size, void* d_ws, size_t ws_size,
                              hipStream_t stream) {
  const float* xdis = (const float*)d_in[0];
  const float* xpre = (const float*)d_in[1];
  const int*   ei_s = (const int*)d_in[2];
  const int*   ei_p = (const int*)d_in[3];
  const float* ew_s = (const float*)d_in[4];
  const float* ew_p = (const float*)d_in[5];
  const float* Wz_s = (const float*)d_in[6];
  const float* bz_s = (const float*)d_in[7];
  const float* Wr_s = (const float*)d_in[8];
  const float* br_s = (const float*)d_in[9];
  const float* Wh_s = (const float*)d_in[10];
  const float* bh_s = (const float*)d_in[11];
  const float* Wz_p = (const float*)d_in[12];
  const float* bz_p = (const float*)d_in[13];
  const float* Wr_p = (const float*)d_in[14];
  const float* br_p = (const float*)d_in[15];
  const float* Wh_p = (const float*)d_in[16];
  const float* bh_p = (const float*)d_in[17];
  const float* W_ro = (const float*)d_in[18];
  const float* b_ro = (const float*)d_in[19];
  const float* W_ag = (const float*)d_in[20];
  const float* b_ag = (const float*)d_in[21];
  float* out = (float*)d_out;
  (void)in_sizes; (void)n_in; (void)out_size; (void)ws_size;

  char* w = (char*)d_ws;
  size_t off = 0;
  auto alloc = [&](size_t bytes) { void* p = w + off; off = (off + bytes + 255) & ~(size_t)255; return p; };

  const size_t rowsXs = (size_t)TCH*NB*NSN, rowsXp = (size_t)TCH*NB*NPN;

  float* Ms_s = (float*)alloc(4*NSN*NSN*sizeof(float));
  float* Ms_p = (float*)alloc(2*NPN*NPN*sizeof(float));
  float* Mbig_s = (float*)alloc(NSN*100*sizeof(float));
  float* Mbig_p = (float*)alloc(NPN*24*sizeof(float));
  half_t* WX_s = (half_t*)alloc((size_t)768*KHS*2);
  half_t* WX_p = (half_t*)alloc((size_t)768*KHP*2);
  half_t* WHzr_s = (half_t*)alloc((size_t)2560*256*2);
  half_t* WHh_s  = (half_t*)alloc((size_t)1280*256*2);
  half_t* WHzr_p = (half_t*)alloc((size_t)1536*256*2);
  half_t* WHh_p  = (half_t*)alloc((size_t)768*256*2);
  half_t* XT_s = (half_t*)alloc(rowsXs*KHS*2);
  half_t* XT_p = (half_t*)alloc(rowsXp*KHP*2);
  half_t* Px_s = (half_t*)alloc((size_t)TT*NB*NSN*NPRE*2);
  half_t* Px_p = (half_t*)alloc((size_t)TT*NB*NPN*NPRE*2);
  float* H  = (float*)alloc((size_t)NB*NN*256*4);
  float* Z  = (float*)alloc((size_t)NB*NN*256*4);
  half_t* Hf  = (half_t*)alloc((size_t)(NB*NN*256 + 32*256)*2);   // +pad for OOB A reads
  half_t* gHf = (half_t*)alloc((size_t)(NB*NN*256 + 32*256)*2);
  half_t* Hf_s = Hf,  * Hf_p = Hf + (size_t)NB*NSN*256;
  half_t* gHf_s = gHf, * gHf_p = gHf + (size_t)NB*NSN*256;

  graph_build<<<1, 64, 0, stream>>>(ei_s, ew_s, ei_p, ew_p, Ms_s, Ms_p, Mbig_s, Mbig_p);
  prep_w<<<1024, 256, 0, stream>>>(Wz_s, Wr_s, Wh_s, Wz_p, Wr_p, Wh_p,
                                   WX_s, WX_p, WHzr_s, WHh_s, WHzr_p, WHh_p);
  const long nH = (long)NB*NN*256;
  zero_f<<<(nH + 255)/256, 256, 0, stream>>>(H, nH);
  zero_f<<<(nH/2 + 255)/256, 256, 0, stream>>>((float*)Hf, nH/2);

  // ---- precompute Px ----
  for (int t0 = 0; t0 < TT; t0 += TCH) {
    chebx<<<2*NB*TCH, 256, 0, stream>>>(xdis, xpre, Ms_s, Ms_p, XT_s, XT_p, t0);
    gemm_pre<<<224*6, 512, 0, stream>>>(
        XT_s, WX_s, KHS, 160, 6,
        XT_p, WX_p, KHP,
        Px_s + (size_t)t0*NB*NSN*NPRE, Px_p + (size_t)t0*NB*NPN*NPRE,
        bz_s, br_s, bh_s, bz_p, br_p, bh_p);
  }

  // ---- recurrence: 2 fused dispatches per step ----
  for (int t = 0; t < TT; ++t) {
    const half_t* PxS = Px_s + (size_t)t*NB*NSN*NPRE;
    const half_t* PxP = Px_p + (size_t)t*NB*NPN*NPRE;
    rec2_k<0><<<NB*4 + 32*4, 512, 0, stream>>>(
        Hf_s, Hf_p, WHzr_s, WHzr_p, PxS, PxP, Mbig_s, Mbig_p,
        H, Z, gHf_s, gHf_p, nullptr, NB*4);
    rec2_k<1><<<NB*2 + 32*2, 512, 0, stream>>>(
        gHf_s, gHf_p, WHh_s, WHh_p, PxS, PxP, Mbig_s, Mbig_p,
        H, Z, Hf_s, Hf_p, H, NB*2);
  }
  readout_k<<<NB, 256, 0, stream>>>(H, W_ro, b_ro, W_ag, b_ag, out);
}